// Round 7
// baseline (521.893 us; speedup 1.0000x reference)
//
#include <hip/hip_runtime.h>
#include <math.h>
#include <stdint.h>

#define N_NODES 20000
#define M_PAD 20032            // 313 * 64
#define N_EDGES 320000
#define N_GRAPHS 64
#define DIN 128
#define H 256
#define POOL_W 768
#define CHUNK 40               // edges per wave in agg3
#define NCHUNK (N_EDGES / CHUNK)   // 8000 (exact)

typedef __attribute__((ext_vector_type(8))) short bf16x8;   // 8 bf16 = 4 VGPRs
typedef __attribute__((ext_vector_type(4))) float f32x4;
typedef __attribute__((ext_vector_type(4))) unsigned int u32x4;
typedef __attribute__((ext_vector_type(2))) unsigned int u32x2;
typedef _Float16 h2 __attribute__((ext_vector_type(2)));    // packed f16 pair (1 VGPR)

__device__ __forceinline__ unsigned short f2bf(float f) {
    unsigned u = __builtin_bit_cast(unsigned, f);
    u += 0x7FFFu + ((u >> 16) & 1u);          // round-to-nearest-even
    return (unsigned short)(u >> 16);
}
__device__ __forceinline__ float bf2f(unsigned short u) {
    return __builtin_bit_cast(float, (unsigned)u << 16);
}
__device__ __forceinline__ unsigned short f2h(float f) {
    const _Float16 h = (_Float16)f;
    return __builtin_bit_cast(unsigned short, h);
}

#if __has_builtin(__builtin_amdgcn_fdot2)
#define DOT2(a, b, c) __builtin_amdgcn_fdot2((a), (b), (c), false)
#else
__device__ __forceinline__ float dot2_fallback(h2 a, h2 b, float c) {
    return fmaf((float)a.x, (float)b.x, fmaf((float)a.y, (float)b.y, c));
}
#define DOT2(a, b, c) dot2_fallback((a), (b), (c))
#endif

// ---------------------------------------------------------------------------
// Batched converts + zero jobs: 12 jobs, one launch.
// mode 0: fp32 -> bf16   mode 1: fp32 -> f16   mode 2: zero fill
// ---------------------------------------------------------------------------
struct CvtJob  { const float* s; unsigned short* d; int n4; int mode; };
struct CvtJobs { CvtJob j[12]; };

__global__ __launch_bounds__(256) void cvt_all(CvtJobs jobs)
{
    const CvtJob J = jobs.j[blockIdx.y];
    if (J.mode == 2) {
        const ushort4 z = {0, 0, 0, 0};
        for (int i = blockIdx.x * 256 + threadIdx.x; i < J.n4; i += gridDim.x * 256)
            ((ushort4*)J.d)[i] = z;
        return;
    }
    if (J.mode == 1) {
        for (int i = blockIdx.x * 256 + threadIdx.x; i < J.n4; i += gridDim.x * 256) {
            const float4 v = ((const float4*)J.s)[i];
            ushort4 r;
            r.x = f2h(v.x); r.y = f2h(v.y); r.z = f2h(v.z); r.w = f2h(v.w);
            ((ushort4*)J.d)[i] = r;
        }
        return;
    }
    for (int i = blockIdx.x * 256 + threadIdx.x; i < J.n4; i += gridDim.x * 256) {
        const float4 v = ((const float4*)J.s)[i];
        ushort4 r;
        r.x = f2bf(v.x); r.y = f2bf(v.y); r.z = f2bf(v.z); r.w = f2bf(v.w);
        ((ushort4*)J.d)[i] = r;
    }
}

// ---------------------------------------------------------------------------
// CSR build
// ---------------------------------------------------------------------------
__global__ __launch_bounds__(256) void hist_kernel(const int* __restrict__ dst,
                                                   int* __restrict__ deg)
{
    const int i = blockIdx.x * 256 + threadIdx.x;
    if (i < N_EDGES) atomicAdd(deg + dst[i], 1);
}

// shfl scan; writes off and cursor; tail threads also compute graph starts
__global__ __launch_bounds__(1024) void scan_kernel(const int* __restrict__ deg,
                                                    int* __restrict__ off,
                                                    int* __restrict__ cur,
                                                    const int* __restrict__ batch,
                                                    int* __restrict__ start)
{
    __shared__ int wsum[16];
    __shared__ int carry;
    const int tid = threadIdx.x, wave = tid >> 6, lane = tid & 63;
    if (tid == 0) carry = 0;
    __syncthreads();
    for (int base = 0; base < N_NODES; base += 1024) {
        const int i = base + tid;
        const int v = (i < N_NODES) ? deg[i] : 0;
        int s = v;
#pragma unroll
        for (int d = 1; d < 64; d <<= 1) {
            const int t = __shfl_up(s, d);
            if (lane >= d) s += t;
        }
        if (lane == 63) wsum[wave] = s;
        __syncthreads();
        if (wave == 0) {
            int t = (lane < 16) ? wsum[lane] : 0;
#pragma unroll
            for (int d = 1; d < 16; d <<= 1) {
                const int u = __shfl_up(t, d);
                if (lane >= d) t += u;
            }
            if (lane < 16) wsum[lane] = t;
        }
        __syncthreads();
        const int wbase = (wave == 0) ? 0 : wsum[wave - 1];
        if (i < N_NODES) {
            const int o = carry + wbase + s - v;
            off[i] = o;
            cur[i] = o;
        }
        const int tot = wsum[15];
        __syncthreads();
        if (tid == 0) carry += tot;
        __syncthreads();
    }
    if (tid == 0) off[N_NODES] = carry;

    // graph boundaries (batch is sorted)
    if (tid <= N_GRAPHS) {
        if (tid == N_GRAPHS) { start[N_GRAPHS] = N_NODES; }
        else {
            int lo = 0, hi = N_NODES;
            while (lo < hi) { const int mid = (lo + hi) >> 1; if (batch[mid] < tid) lo = mid + 1; else hi = mid; }
            start[tid] = lo;
        }
    }
}

// chunk -> first-node map for edge-parallel agg3: cmap[w] = lower_bound(off, w*CHUNK)
__global__ __launch_bounds__(256) void chunkmap_kernel(const int* __restrict__ off,
                                                       int* __restrict__ cmap)
{
    const int w = blockIdx.x * 256 + threadIdx.x;
    if (w > NCHUNK) return;
    if (w == NCHUNK) { cmap[w] = N_NODES; return; }
    const int target = w * CHUNK;
    int lo = 0, hi = N_NODES;           // first n with off[n] >= target
    while (lo < hi) { const int mid = (lo + hi) >> 1; if (off[mid] < target) lo = mid + 1; else hi = mid; }
    cmap[w] = lo;
}

// scatter v2: build CSR-sorted src ids AND CSR-sorted f16 edge features in
// one pass (reads original fp32 ea).
__global__ __launch_bounds__(256) void scatter_kernel(
    const int* __restrict__ src, const int* __restrict__ dst,
    const float* __restrict__ ea, int* __restrict__ cursor,
    int* __restrict__ ssrc, unsigned short* __restrict__ eas)
{
    const int e = blockIdx.x * 256 + threadIdx.x;
    if (e < N_EDGES) {
        const int p = atomicAdd(cursor + dst[e], 1);
        ssrc[p] = src[e];
        const float4* er = (const float4*)(ea + (size_t)e * 16);
        unsigned short* dr = eas + (size_t)p * 16;
        ushort4* d4 = (ushort4*)dr;
#pragma unroll
        for (int q = 0; q < 4; ++q) {
            const float4 v = er[q];
            ushort4 r;
            r.x = f2h(v.x); r.y = f2h(v.y); r.z = f2h(v.z); r.w = f2h(v.w);
            d4[q] = r;
        }
    }
}

// ---------------------------------------------------------------------------
// agg3 v6b — edge-parallel segmented aggregation (v6 structure; crash fix).
// v6 CRASHED: the pipeline prefetches ssrc[p+4..p+11]; past pend on tail
// chunks those indices run into the UNINITIALIZED ssrc pad, and the garbage
// value is DEREFERENCED as a node id by ldx -> wild address -> page fault.
// Fix: clamp ldsrc's index to E-1 (valid node id, loaded but never computed;
// edge_compute stops at pend). eas pad reads stay unclamped: within the
// allocation, data never consumed.
// 8000 waves x 40-edge CSR chunks (boundaries node-rounded via cmap);
// depth-4 in-place pipeline runs across node boundaries; wave-uniform SALU
// flush at p==off[n+1]. No atomics.
// out[v] = bf16( x[v] + sum_e relu(x[src] + ea@We.T + be) )
// ---------------------------------------------------------------------------
template<int IN>
__global__ __launch_bounds__(256) void agg3(
    const unsigned short* __restrict__ xb,   // [M_PAD, IN] bf16
    const unsigned short* __restrict__ eas,  // [E+16,16] f16, CSR order
    const int* __restrict__ ssrc,            // [E+16] src, CSR order
    const int* __restrict__ off,             // [N+1]
    const int* __restrict__ cmap,            // [NCHUNK+1]
    const unsigned short* __restrict__ Weh,  // [IN,16] f16
    const float* __restrict__ be,
    unsigned short* __restrict__ out)        // [M_PAD, IN] bf16
{
    constexpr int CPL = IN / 64;             // 2 (layer1) or 4
    constexpr int XW  = CPL / 2;             // x-row dwords per lane: 1 or 2
    const int lane = threadIdx.x & 63;
    const int wid  = blockIdx.x * 4 + (threadIdx.x >> 6);
    const int c0 = lane * CPL;
    const int zd = __builtin_amdgcn_mbcnt_lo(0u, 0u);   // divergent zero: defeats SMEM scalarization

    // weights: CPL rows x 16 f16 — loaded once, best-effort pinned
    u32x4 wlo[CPL], whi[CPL];
    float bias[CPL], acc[CPL];
#pragma unroll
    for (int j = 0; j < CPL; ++j) {
        const u32x4* wr = (const u32x4*)(Weh + (size_t)(c0 + j) * 16);
        wlo[j] = wr[0];
        whi[j] = wr[1];
        bias[j] = be[c0 + j];
        acc[j]  = 0.0f;
    }
#pragma unroll
    for (int j = 0; j < CPL; ++j) {
#pragma unroll
        for (int k = 0; k < 4; ++k) {
            { float t = __builtin_bit_cast(float, wlo[j][k]); asm volatile("" : "+v"(t)); wlo[j][k] = __builtin_bit_cast(unsigned int, t); }
            { float t = __builtin_bit_cast(float, whi[j][k]); asm volatile("" : "+v"(t)); whi[j][k] = __builtin_bit_cast(unsigned int, t); }
        }
        asm volatile("" : "+v"(bias[j]));
    }

    int n          = __builtin_amdgcn_readfirstlane(cmap[wid]);
    const int nend = __builtin_amdgcn_readfirstlane(cmap[wid + 1]);
    if (n >= nend) return;                    // giant node spans this chunk
    int p          = __builtin_amdgcn_readfirstlane(off[n]);
    const int pend = __builtin_amdgcn_readfirstlane(off[nend]);

    auto flush = [&](int nn) {                // store bf16(x[nn] + acc); acc = 0
        if constexpr (XW == 2) {
            const u32x2 xs = *(const u32x2*)(xb + (size_t)nn * IN + c0);
            const float x0 = __builtin_bit_cast(float, xs[0] << 16);
            const float x1 = __builtin_bit_cast(float, xs[0] & 0xFFFF0000u);
            const float x2 = __builtin_bit_cast(float, xs[1] << 16);
            const float x3 = __builtin_bit_cast(float, xs[1] & 0xFFFF0000u);
            u32x2 o;
            o[0] = (unsigned)f2bf(x0 + acc[0]) | ((unsigned)f2bf(x1 + acc[1]) << 16);
            o[1] = (unsigned)f2bf(x2 + acc[2]) | ((unsigned)f2bf(x3 + acc[3]) << 16);
            *(u32x2*)(out + (size_t)nn * IN + c0) = o;
        } else {
            const unsigned int xs = *(const unsigned int*)(xb + (size_t)nn * IN + c0);
            const float x0 = __builtin_bit_cast(float, xs << 16);
            const float x1 = __builtin_bit_cast(float, xs & 0xFFFF0000u);
            const unsigned int o =
                (unsigned)f2bf(x0 + acc[0]) | ((unsigned)f2bf(x1 + acc[1]) << 16);
            *(unsigned int*)(out + (size_t)nn * IN + c0) = o;
        }
#pragma unroll
        for (int j = 0; j < CPL; ++j) acc[j] = 0.0f;
    };

    // zero-degree nodes at the head of the range
    int p1 = __builtin_amdgcn_readfirstlane(off[n + 1]);
    while (p1 == p) {
        flush(n); ++n;
        if (n >= nend) return;
        p1 = __builtin_amdgcn_readfirstlane(off[n + 1]);
    }
    // here: current node n non-empty, p = off[n] < p1 <= pend

    auto ldeL = [&](int q) -> u32x4 {        // pad reads OK: in-allocation, unused
        return ((const u32x4*)(eas + (size_t)(q + zd) * 16))[0];
    };
    auto ldeH = [&](int q) -> u32x4 {
        return ((const u32x4*)(eas + (size_t)(q + zd) * 16))[1];
    };
    auto ldsrc = [&](int q) -> int {         // CLAMPED: result is dereferenced
        const int qc = (q < N_EDGES) ? q : (N_EDGES - 1);
        return ssrc[qc + zd];
    };
    auto ldx = [&](int s) -> u32x2 {
        if constexpr (XW == 2) {
            return *(const u32x2*)(xb + (size_t)s * IN + c0);
        } else {
            u32x2 r;
            r[0] = *(const unsigned int*)(xb + (size_t)s * IN + c0);
            r[1] = 0u;
            return r;
        }
    };
    auto edge_compute = [&](u32x4 eL, u32x4 eH, u32x2 xw) {
        float m[CPL];
#pragma unroll
        for (int j = 0; j < CPL; ++j) m[j] = bias[j];
#pragma unroll
        for (int k = 0; k < 4; ++k) {
            const h2 ep = __builtin_bit_cast(h2, eL[k]);
#pragma unroll
            for (int j = 0; j < CPL; ++j)
                m[j] = DOT2(ep, __builtin_bit_cast(h2, wlo[j][k]), m[j]);
        }
#pragma unroll
        for (int k = 0; k < 4; ++k) {
            const h2 ep = __builtin_bit_cast(h2, eH[k]);
#pragma unroll
            for (int j = 0; j < CPL; ++j)
                m[j] = DOT2(ep, __builtin_bit_cast(h2, whi[j][k]), m[j]);
        }
#pragma unroll
        for (int j = 0; j < CPL; ++j) {
            const unsigned int word = xw[j >> 1];
            const float xf = __builtin_bit_cast(float,
                (j & 1) ? (word & 0xFFFF0000u) : (word << 16));
            acc[j] += fmaxf(m[j] + xf, 0.0f);
        }
    };
    // flush current node + any zero-degree ties at position p
    auto adv = [&]() {
        flush(n); ++n;
        while (n < nend) {
            p1 = __builtin_amdgcn_readfirstlane(off[n + 1]);
            if (p1 != p) break;
            flush(n); ++n;
        }
    };

    // depth-4 pipeline, in-place buffers, runs across node boundaries
    int sA = ldsrc(p),     sB = ldsrc(p + 1), sC = ldsrc(p + 2), sD = ldsrc(p + 3);
    u32x4 eLA = ldeL(p),     eHA = ldeH(p);
    u32x4 eLB = ldeL(p + 1), eHB = ldeH(p + 1);
    u32x4 eLC = ldeL(p + 2), eHC = ldeH(p + 2);
    u32x4 eLD = ldeL(p + 3), eHD = ldeH(p + 3);
    u32x2 xA = ldx(sA), xB = ldx(sB), xC = ldx(sC), xD = ldx(sD);
    sA = ldsrc(p + 4); sB = ldsrc(p + 5); sC = ldsrc(p + 6); sD = ldsrc(p + 7);

    for (;;) {
        edge_compute(eLA, eHA, xA);
        eLA = ldeL(p + 4); eHA = ldeH(p + 4); xA = ldx(sA); sA = ldsrc(p + 8);
        ++p; if (p == p1) adv();
        if (p >= pend) break;

        edge_compute(eLB, eHB, xB);
        eLB = ldeL(p + 4); eHB = ldeH(p + 4); xB = ldx(sB); sB = ldsrc(p + 8);
        ++p; if (p == p1) adv();
        if (p >= pend) break;

        edge_compute(eLC, eHC, xC);
        eLC = ldeL(p + 4); eHC = ldeH(p + 4); xC = ldx(sC); sC = ldsrc(p + 8);
        ++p; if (p == p1) adv();
        if (p >= pend) break;

        edge_compute(eLD, eHD, xD);
        eLD = ldeL(p + 4); eHD = ldeH(p + 4); xD = ldx(sD); sD = ldsrc(p + 8);
        ++p; if (p == p1) adv();
        if (p >= pend) break;
    }
    // safety: trailing zero-degree nodes (normally handled by adv)
    while (n < nend) { flush(n); ++n; }
}

// ---------------------------------------------------------------------------
// B-in-register streaming GEMM v2 (best measured config, R9):
// grid (313,2), 4 waves/block, wave owns 32 cols with K resident in regs;
// 4 chunks of 16 rows with 2-deep prefetch. No LDS, no barriers.
// EPI 0: BN(eval)+relu -> bf16 (all rows)   EPI 1: bias+relu (rows < N)
// ---------------------------------------------------------------------------
template<int K, int EPI>
__global__ __launch_bounds__(256) void gemm_breg2(
    const unsigned short* __restrict__ A,    // [M_PAD, K]
    const unsigned short* __restrict__ W,    // [256, K]
    const float* __restrict__ bias,
    const float* __restrict__ gsc, const float* __restrict__ bsh,
    unsigned short* __restrict__ out)        // [M_PAD, 256]
{
    constexpr int KC = K / 32;               // 4 or 8 k-chunks
    const int w = threadIdx.x >> 6, lane = threadIdx.x & 63;
    const int lm = lane & 15, lq = lane >> 4;
    const int n0 = (blockIdx.y * 4 + w) * 32;
    const int m0 = blockIdx.x * 64;

    // B resident in registers
    bf16x8 B0[KC], B1[KC];
    {
        const unsigned short* Wp0 = W + (size_t)(n0 + lm) * K + lq * 8;
        const unsigned short* Wp1 = W + (size_t)(n0 + 16 + lm) * K + lq * 8;
#pragma unroll
        for (int c = 0; c < KC; ++c) {
            B0[c] = *(const bf16x8*)(Wp0 + c * 32);
            B1[c] = *(const bf16x8*)(Wp1 + c * 32);
        }
    }

    const float inv = rsqrtf(1.0f + 1e-5f);
    const float bc0 = bias[n0 + lm],      bc1 = bias[n0 + 16 + lm];
    const float gc0 = (EPI == 0) ? gsc[n0 + lm]      : 0.0f;
    const float gc1 = (EPI == 0) ? gsc[n0 + 16 + lm] : 0.0f;
    const float sc0 = (EPI == 0) ? bsh[n0 + lm]      : 0.0f;
    const float sc1 = (EPI == 0) ? bsh[n0 + 16 + lm] : 0.0f;

    bf16x8 aC[KC], aN[KC];
    {
        const unsigned short* Ap = A + (size_t)(m0 + lm) * K + lq * 8;
#pragma unroll
        for (int c = 0; c < KC; ++c) aC[c] = *(const bf16x8*)(Ap + c * 32);
    }

#pragma unroll
    for (int ch = 0; ch < 4; ++ch) {
        if (ch < 3) {
            const unsigned short* Ap = A + (size_t)(m0 + (ch + 1) * 16 + lm) * K + lq * 8;
#pragma unroll
            for (int c = 0; c < KC; ++c) aN[c] = *(const bf16x8*)(Ap + c * 32);
        }

        f32x4 acc0 = (f32x4){0.f, 0.f, 0.f, 0.f};
        f32x4 acc1 = (f32x4){0.f, 0.f, 0.f, 0.f};
#pragma unroll
        for (int c = 0; c < KC; ++c) {
            acc0 = __builtin_amdgcn_mfma_f32_16x16x32_bf16(aC[c], B0[c], acc0, 0, 0, 0);
            acc1 = __builtin_amdgcn_mfma_f32_16x16x32_bf16(aC[c], B1[c], acc1, 0, 0, 0);
        }

        const int mr = m0 + ch * 16;
#pragma unroll
        for (int r = 0; r < 4; ++r) {
            const int row = mr + lq * 4 + r;
            if (EPI == 1 && row >= N_NODES) continue;
            float v0 = acc0[r] + bc0;
            float v1 = acc1[r] + bc1;
            if (EPI == 0) {
                v0 = fmaxf(v0 * inv * gc0 + sc0, 0.0f);
                v1 = fmaxf(v1 * inv * gc1 + sc1, 0.0f);
            } else {
                v0 = fmaxf(v0, 0.0f);
                v1 = fmaxf(v1, 0.0f);
            }
            out[(size_t)row * H + n0 + lm]      = f2bf(v0);
            out[(size_t)row * H + n0 + 16 + lm] = f2bf(v1);
        }

#pragma unroll
        for (int c = 0; c < KC; ++c) aC[c] = aN[c];
    }
}

// ---------------------------------------------------------------------------
// Parallel mean-pool: grid (192, RSPLIT). Block (g, layer, chunk) reduces
// ~rows/RSPLIT rows and atomicAdds one partial per column into pool.
// ---------------------------------------------------------------------------
#define RSPLIT 6
__global__ __launch_bounds__(256) void pool2(
    const unsigned short* __restrict__ h1, const unsigned short* __restrict__ h2,
    const unsigned short* __restrict__ h3, const int* __restrict__ start,
    float* __restrict__ pool)
{
    const int g = blockIdx.x & 63, layer = blockIdx.x >> 6;
    const unsigned short* h = (layer == 0) ? h1 : (layer == 1) ? h2 : h3;
    const int r0 = start[g], r1 = start[g + 1];
    const int nr = r1 - r0;
    if (nr <= 0) return;
    const int chunk = (nr + RSPLIT - 1) / RSPLIT;
    const int rs = r0 + blockIdx.y * chunk;
    const int re = (rs + chunk < r1) ? rs + chunk : r1;
    if (rs >= re) return;

    const int c = threadIdx.x;
    float s0 = 0.f, s1 = 0.f, s2 = 0.f, s3 = 0.f;
    int r = rs;
    for (; r + 4 <= re; r += 4) {
        s0 += bf2f(h[(size_t)(r + 0) * H + c]);
        s1 += bf2f(h[(size_t)(r + 1) * H + c]);
        s2 += bf2f(h[(size_t)(r + 2) * H + c]);
        s3 += bf2f(h[(size_t)(r + 3) * H + c]);
    }
    for (; r < re; ++r) s0 += bf2f(h[(size_t)r * H + c]);
    atomicAdd(&pool[(size_t)g * POOL_W + layer * 256 + c], s0 + s1 + s2 + s3);
}

// ---------------------------------------------------------------------------
// FC head v2 (measured win in R4; unchanged): (64 x 12) blocks, lane-parallel
// 768-dot per output + shfl_xor reduce; FC2 folded via per-wave atomicAdd.
// ---------------------------------------------------------------------------
__global__ __launch_bounds__(256) void fc_head(
    const float* __restrict__ pool, const int* __restrict__ start,
    const float* __restrict__ L1w, const float* __restrict__ L1b,
    const float* __restrict__ L2w, float* __restrict__ gsum)
{
    const int g = blockIdx.x;
    __shared__ float p[POOL_W];

    const float rc = 1.0f / fmaxf((float)(start[g + 1] - start[g]), 1.0f);
    for (int i = threadIdx.x; i < POOL_W; i += 256)
        p[i] = pool[(size_t)g * POOL_W + i] * rc;
    __syncthreads();

    const int wv = threadIdx.x >> 6, lane = threadIdx.x & 63;
    const float4* p4 = (const float4*)p;
    const float4 pa = p4[lane], pb = p4[lane + 64], pc = p4[lane + 128];

    const int ob = blockIdx.y * 64 + wv * 16;
    float part = 0.0f;
#pragma unroll 4
    for (int t = 0; t < 16; ++t) {
        const int o = ob + t;
        const float4* wr = (const float4*)(L1w + (size_t)o * POOL_W);
        const float4 a = wr[lane], b = wr[lane + 64], c = wr[lane + 128];
        float acc = a.x * pa.x + a.y * pa.y + a.z * pa.z + a.w * pa.w
                  + b.x * pb.x + b.y * pb.y + b.z * pb.z + b.w * pb.w
                  + c.x * pc.x + c.y * pc.y + c.z * pc.z + c.w * pc.w;
#pragma unroll
        for (int off = 32; off > 0; off >>= 1) acc += __shfl_xor(acc, off);
        if (lane == 0) part += fmaxf(acc + L1b[o], 0.0f) * L2w[o];
    }
    if (lane == 0) atomicAdd(&gsum[g], part);
}

__global__ __launch_bounds__(64) void sig_kernel(
    const float* __restrict__ gsum, const float* __restrict__ L2b,
    float* __restrict__ out)
{
    const int g = threadIdx.x;
    if (g < N_GRAPHS) out[g] = 1.0f / (1.0f + expf(-(gsum[g] + L2b[0])));
}

// ---------------------------------------------------------------------------
extern "C" void kernel_launch(void* const* d_in, const int* in_sizes, int n_in,
                              void* d_out, int out_size, void* d_ws, size_t ws_size,
                              hipStream_t stream)
{
    const float* x     = (const float*)d_in[0];
    const float* ea    = (const float*)d_in[1];
    const int*   src   = (const int*)d_in[2];
    const int*   dst   = (const int*)d_in[3];
    const int*   batch = (const int*)d_in[4];

    const float* We[3]; const float* be[3]; const float* Wa[3]; const float* ba[3];
    const float* gg[3]; const float* bt[3]; const float* Wb[3]; const float* bb[3];
    for (int l = 0; l < 3; ++l) {
        const int o = 5 + 8 * l;
        We[l] = (const float*)d_in[o + 0]; be[l] = (const float*)d_in[o + 1];
        Wa[l] = (const float*)d_in[o + 2]; ba[l] = (const float*)d_in[o + 3];
        gg[l] = (const float*)d_in[o + 4]; bt[l] = (const float*)d_in[o + 5];
        Wb[l] = (const float*)d_in[o + 6]; bb[l] = (const float*)d_in[o + 7];
    }
    const float* L1w = (const float*)d_in[29];
    const float* L1b = (const float*)d_in[30];
    const float* L2w = (const float*)d_in[31];
    const float* L2b = (const float*)d_in[32];

    // ---- workspace layout ----
    float* pool   = (float*)d_ws;                              // 64*768
    float* gsum   = pool + (size_t)N_GRAPHS * POOL_W;          // 64 (zeroed with pool)
    int*   deg    = (int*)(gsum + N_GRAPHS);                   // N
    int*   off    = deg + N_NODES;                             // N+1
    int*   cursor = off + N_NODES + 1;                         // N
    int*   start  = cursor + N_NODES;                          // 72
    int*   cmap   = start + 72;                                // NCHUNK+1
    int*   ssrc   = (int*)((((uintptr_t)(cmap + NCHUNK + 1)) + 31) & ~(uintptr_t)31);  // E+16 ints, CSR
    unsigned short* eas = (unsigned short*)((((uintptr_t)(ssrc + N_EDGES + 16)) + 31) & ~(uintptr_t)31); // [E+16,16] f16 CSR
    unsigned short* xb = (unsigned short*)((((uintptr_t)(eas + (size_t)(N_EDGES + 16) * 16)) + 31) & ~(uintptr_t)31);
    unsigned short* u  = xb + (size_t)M_PAD * DIN;             // [M_PAD,256] (layer1 uses 128)
    unsigned short* tT = u  + (size_t)M_PAD * H;               // [M_PAD,256] intermediate
    unsigned short* h1 = tT + (size_t)M_PAD * H;
    unsigned short* h2 = h1 + (size_t)M_PAD * H;
    unsigned short* h3 = h2 + (size_t)M_PAD * H;
    unsigned short* wbf[6];
    wbf[0] = h3 + (size_t)M_PAD * H;                           // Wa1 [256,128]
    wbf[1] = wbf[0] + H * DIN;
    for (int i = 2; i < 6; ++i) wbf[i] = wbf[i - 1] + H * H;
    unsigned short* weh[3];
    weh[0] = wbf[5] + H * H;                                   // We1 [128,16] f16
    weh[1] = weh[0] + DIN * 16;                                // We2 [256,16] f16
    weh[2] = weh[1] + H * 16;                                  // We3 [256,16] f16

    // batched converts + deg/pool+gsum zeroing in one launch (12 jobs)
    CvtJobs jobs;
    jobs.j[0]  = { x,       xb,                    N_NODES * DIN / 4,       0 };
    jobs.j[1]  = { Wa[0],   wbf[0],                H * DIN / 4,             0 };
    jobs.j[2]  = { Wb[0],   wbf[1],                H * H / 4,               0 };
    jobs.j[3]  = { Wa[1],   wbf[2],                H * H / 4,               0 };
    jobs.j[4]  = { Wb[1],   wbf[3],                H * H / 4,               0 };
    jobs.j[5]  = { Wa[2],   wbf[4],                H * H / 4,               0 };
    jobs.j[6]  = { Wb[2],   wbf[5],                H * H / 4,               0 };
    jobs.j[7]  = { nullptr, (unsigned short*)deg,  N_NODES * 4 / 8,         2 };  // zero N ints
    jobs.j[8]  = { nullptr, (unsigned short*)pool, (N_GRAPHS * POOL_W + N_GRAPHS) * 4 / 8, 2 }; // zero pool+gsum
    jobs.j[9]  = { We[0],   weh[0],                DIN * 16 / 4,            1 };
    jobs.j[10] = { We[1],   weh[1],                H * 16 / 4,              1 };
    jobs.j[11] = { We[2],   weh[2],                H * 16 / 4,              1 };
    cvt_all<<<dim3(320, 12), 256, 0, stream>>>(jobs);

    // CSR + graph boundaries; chunk map; scatter builds CSR-sorted (src, ea_f16)
    hist_kernel<<<(N_EDGES + 255) / 256, 256, 0, stream>>>(dst, deg);
    scan_kernel<<<1, 1024, 0, stream>>>(deg, off, cursor, batch, start);
    chunkmap_kernel<<<(NCHUNK + 256) / 256, 256, 0, stream>>>(off, cmap);
    scatter_kernel<<<(N_EDGES + 255) / 256, 256, 0, stream>>>(src, dst, ea, cursor, ssrc, eas);

    const int  agrid = NCHUNK / 4;              // agg3: 1 chunk/wave, 4 waves/block
    const dim3 ggrid(M_PAD / 64, 2);            // (313, 2)

    // ---- layer 1 (in=128) ----
    agg3<DIN><<<agrid, 256, 0, stream>>>(xb, eas, ssrc, off, cmap, weh[0], be[0], u);
    gemm_breg2<DIN, 0><<<ggrid, 256, 0, stream>>>(u, wbf[0], ba[0], gg[0], bt[0], tT);
    gemm_breg2<H,   1><<<ggrid, 256, 0, stream>>>(tT, wbf[1], bb[0], nullptr, nullptr, h1);
    // ---- layer 2 ----
    agg3<H><<<agrid, 256, 0, stream>>>(h1, eas, ssrc, off, cmap, weh[1], be[1], u);
    gemm_breg2<H, 0><<<ggrid, 256, 0, stream>>>(u, wbf[2], ba[1], gg[1], bt[1], tT);
    gemm_breg2<H, 1><<<ggrid, 256, 0, stream>>>(tT, wbf[3], bb[1], nullptr, nullptr, h2);
    // ---- layer 3 ----
    agg3<H><<<agrid, 256, 0, stream>>>(h2, eas, ssrc, off, cmap, weh[2], be[2], u);
    gemm_breg2<H, 0><<<ggrid, 256, 0, stream>>>(u, wbf[4], ba[2], gg[2], bt[2], tT);
    gemm_breg2<H, 1><<<ggrid, 256, 0, stream>>>(tT, wbf[5], bb[2], nullptr, nullptr, h3);

    // parallel mean-pool + head
    pool2<<<dim3(3 * N_GRAPHS, RSPLIT), 256, 0, stream>>>(h1, h2, h3, start, pool);
    fc_head<<<dim3(N_GRAPHS, POOL_W / 64), 256, 0, stream>>>(pool, start, L1w, L1b, L2w, gsum);
    sig_kernel<<<1, 64, 0, stream>>>(gsum, L2b, (float*)d_out);
}

// Round 8
// 481.178 us; speedup vs baseline: 1.0846x; 1.0846x over previous
//
#include <hip/hip_runtime.h>
#include <math.h>
#include <stdint.h>

#define N_NODES 20000
#define M_PAD 20032            // 313 * 64
#define N_EDGES 320000
#define N_GRAPHS 64
#define DIN 128
#define H 256
#define POOL_W 768
#define CHUNK 40               // edges per wave in agg3
#define NCHUNK (N_EDGES / CHUNK)   // 8000 (exact)

typedef __attribute__((ext_vector_type(8))) short bf16x8;   // 8 bf16 = 4 VGPRs
typedef __attribute__((ext_vector_type(4))) float f32x4;
typedef __attribute__((ext_vector_type(4))) unsigned int u32x4;
typedef __attribute__((ext_vector_type(2))) unsigned int u32x2;
typedef _Float16 h2 __attribute__((ext_vector_type(2)));    // packed f16 pair (1 VGPR)

__device__ __forceinline__ unsigned short f2bf(float f) {
    unsigned u = __builtin_bit_cast(unsigned, f);
    u += 0x7FFFu + ((u >> 16) & 1u);          // round-to-nearest-even
    return (unsigned short)(u >> 16);
}
__device__ __forceinline__ float bf2f(unsigned short u) {
    return __builtin_bit_cast(float, (unsigned)u << 16);
}
__device__ __forceinline__ unsigned short f2h(float f) {
    const _Float16 h = (_Float16)f;
    return __builtin_bit_cast(unsigned short, h);
}

#if __has_builtin(__builtin_amdgcn_fdot2)
#define DOT2(a, b, c) __builtin_amdgcn_fdot2((a), (b), (c), false)
#else
__device__ __forceinline__ float dot2_fallback(h2 a, h2 b, float c) {
    return fmaf((float)a.x, (float)b.x, fmaf((float)a.y, (float)b.y, c));
}
#define DOT2(a, b, c) dot2_fallback((a), (b), (c))
#endif

// ---------------------------------------------------------------------------
// Batched converts + zero jobs: 12 jobs, one launch.
// mode 0: fp32 -> bf16   mode 1: fp32 -> f16   mode 2: zero fill
// ---------------------------------------------------------------------------
struct CvtJob  { const float* s; unsigned short* d; int n4; int mode; };
struct CvtJobs { CvtJob j[12]; };

__global__ __launch_bounds__(256) void cvt_all(CvtJobs jobs)
{
    const CvtJob J = jobs.j[blockIdx.y];
    if (J.mode == 2) {
        const ushort4 z = {0, 0, 0, 0};
        for (int i = blockIdx.x * 256 + threadIdx.x; i < J.n4; i += gridDim.x * 256)
            ((ushort4*)J.d)[i] = z;
        return;
    }
    if (J.mode == 1) {
        for (int i = blockIdx.x * 256 + threadIdx.x; i < J.n4; i += gridDim.x * 256) {
            const float4 v = ((const float4*)J.s)[i];
            ushort4 r;
            r.x = f2h(v.x); r.y = f2h(v.y); r.z = f2h(v.z); r.w = f2h(v.w);
            ((ushort4*)J.d)[i] = r;
        }
        return;
    }
    for (int i = blockIdx.x * 256 + threadIdx.x; i < J.n4; i += gridDim.x * 256) {
        const float4 v = ((const float4*)J.s)[i];
        ushort4 r;
        r.x = f2bf(v.x); r.y = f2bf(v.y); r.z = f2bf(v.z); r.w = f2bf(v.w);
        ((ushort4*)J.d)[i] = r;
    }
}

// ---------------------------------------------------------------------------
// CSR build
// ---------------------------------------------------------------------------
__global__ __launch_bounds__(256) void hist_kernel(const int* __restrict__ dst,
                                                   int* __restrict__ deg)
{
    const int i = blockIdx.x * 256 + threadIdx.x;
    if (i < N_EDGES) atomicAdd(deg + dst[i], 1);
}

// shfl scan; writes off and cursor; tail threads also compute graph starts
__global__ __launch_bounds__(1024) void scan_kernel(const int* __restrict__ deg,
                                                    int* __restrict__ off,
                                                    int* __restrict__ cur,
                                                    const int* __restrict__ batch,
                                                    int* __restrict__ start)
{
    __shared__ int wsum[16];
    __shared__ int carry;
    const int tid = threadIdx.x, wave = tid >> 6, lane = tid & 63;
    if (tid == 0) carry = 0;
    __syncthreads();
    for (int base = 0; base < N_NODES; base += 1024) {
        const int i = base + tid;
        const int v = (i < N_NODES) ? deg[i] : 0;
        int s = v;
#pragma unroll
        for (int d = 1; d < 64; d <<= 1) {
            const int t = __shfl_up(s, d);
            if (lane >= d) s += t;
        }
        if (lane == 63) wsum[wave] = s;
        __syncthreads();
        if (wave == 0) {
            int t = (lane < 16) ? wsum[lane] : 0;
#pragma unroll
            for (int d = 1; d < 16; d <<= 1) {
                const int u = __shfl_up(t, d);
                if (lane >= d) t += u;
            }
            if (lane < 16) wsum[lane] = t;
        }
        __syncthreads();
        const int wbase = (wave == 0) ? 0 : wsum[wave - 1];
        if (i < N_NODES) {
            const int o = carry + wbase + s - v;
            off[i] = o;
            cur[i] = o;
        }
        const int tot = wsum[15];
        __syncthreads();
        if (tid == 0) carry += tot;
        __syncthreads();
    }
    if (tid == 0) off[N_NODES] = carry;

    // graph boundaries (batch is sorted)
    if (tid <= N_GRAPHS) {
        if (tid == N_GRAPHS) { start[N_GRAPHS] = N_NODES; }
        else {
            int lo = 0, hi = N_NODES;
            while (lo < hi) { const int mid = (lo + hi) >> 1; if (batch[mid] < tid) lo = mid + 1; else hi = mid; }
            start[tid] = lo;
        }
    }
}

// chunk -> first-node map for edge-parallel agg3: cmap[w] = lower_bound(off, w*CHUNK)
__global__ __launch_bounds__(256) void chunkmap_kernel(const int* __restrict__ off,
                                                       int* __restrict__ cmap)
{
    const int w = blockIdx.x * 256 + threadIdx.x;
    if (w > NCHUNK) return;
    if (w == NCHUNK) { cmap[w] = N_NODES; return; }
    const int target = w * CHUNK;
    int lo = 0, hi = N_NODES;           // first n with off[n] >= target
    while (lo < hi) { const int mid = (lo + hi) >> 1; if (off[mid] < target) lo = mid + 1; else hi = mid; }
    cmap[w] = lo;
}

// scatter v2: build CSR-sorted src ids AND CSR-sorted f16 edge features in
// one pass (reads original fp32 ea).
__global__ __launch_bounds__(256) void scatter_kernel(
    const int* __restrict__ src, const int* __restrict__ dst,
    const float* __restrict__ ea, int* __restrict__ cursor,
    int* __restrict__ ssrc, unsigned short* __restrict__ eas)
{
    const int e = blockIdx.x * 256 + threadIdx.x;
    if (e < N_EDGES) {
        const int p = atomicAdd(cursor + dst[e], 1);
        ssrc[p] = src[e];
        const float4* er = (const float4*)(ea + (size_t)e * 16);
        unsigned short* dr = eas + (size_t)p * 16;
        ushort4* d4 = (ushort4*)dr;
#pragma unroll
        for (int q = 0; q < 4; ++q) {
            const float4 v = er[q];
            ushort4 r;
            r.x = f2h(v.x); r.y = f2h(v.y); r.z = f2h(v.z); r.w = f2h(v.w);
            d4[q] = r;
        }
    }
}

// ---------------------------------------------------------------------------
// agg3 v7 — v6b + flush-drain fix. v6b's flush loaded x[node] and used it
// immediately -> compiler emits s_waitcnt vmcnt(0) -> drains the depth-4
// edge prefetch pipeline once per node. v7 keeps the current node's x row
// (xself) prefetched at node-entry (~16 edges before use), so the flush
// wait is a counted vmcnt, not a drain. Zero-degree flushes (rare) keep
// the immediate load. Everything else identical to v6b (passed, 68.7 us).
// out[v] = bf16( x[v] + sum_e relu(x[src] + ea@We.T + be) )
// ---------------------------------------------------------------------------
template<int IN>
__global__ __launch_bounds__(256) void agg3(
    const unsigned short* __restrict__ xb,   // [M_PAD, IN] bf16
    const unsigned short* __restrict__ eas,  // [E+16,16] f16, CSR order
    const int* __restrict__ ssrc,            // [E+16] src, CSR order
    const int* __restrict__ off,             // [N+1]
    const int* __restrict__ cmap,            // [NCHUNK+1]
    const unsigned short* __restrict__ Weh,  // [IN,16] f16
    const float* __restrict__ be,
    unsigned short* __restrict__ out)        // [M_PAD, IN] bf16
{
    constexpr int CPL = IN / 64;             // 2 (layer1) or 4
    constexpr int XW  = CPL / 2;             // x-row dwords per lane: 1 or 2
    const int lane = threadIdx.x & 63;
    const int wid  = blockIdx.x * 4 + (threadIdx.x >> 6);
    const int c0 = lane * CPL;
    const int zd = __builtin_amdgcn_mbcnt_lo(0u, 0u);   // divergent zero: defeats SMEM scalarization

    // weights: CPL rows x 16 f16 — loaded once, best-effort pinned
    u32x4 wlo[CPL], whi[CPL];
    float bias[CPL], acc[CPL];
#pragma unroll
    for (int j = 0; j < CPL; ++j) {
        const u32x4* wr = (const u32x4*)(Weh + (size_t)(c0 + j) * 16);
        wlo[j] = wr[0];
        whi[j] = wr[1];
        bias[j] = be[c0 + j];
        acc[j]  = 0.0f;
    }
#pragma unroll
    for (int j = 0; j < CPL; ++j) {
#pragma unroll
        for (int k = 0; k < 4; ++k) {
            { float t = __builtin_bit_cast(float, wlo[j][k]); asm volatile("" : "+v"(t)); wlo[j][k] = __builtin_bit_cast(unsigned int, t); }
            { float t = __builtin_bit_cast(float, whi[j][k]); asm volatile("" : "+v"(t)); whi[j][k] = __builtin_bit_cast(unsigned int, t); }
        }
        asm volatile("" : "+v"(bias[j]));
    }

    int n          = __builtin_amdgcn_readfirstlane(cmap[wid]);
    const int nend = __builtin_amdgcn_readfirstlane(cmap[wid + 1]);
    if (n >= nend) return;                    // giant node spans this chunk
    int p          = __builtin_amdgcn_readfirstlane(off[n]);
    const int pend = __builtin_amdgcn_readfirstlane(off[nend]);

    auto ldx = [&](int s) -> u32x2 {          // row of xb (src gather or self)
        if constexpr (XW == 2) {
            return *(const u32x2*)(xb + (size_t)s * IN + c0);
        } else {
            u32x2 r;
            r[0] = *(const unsigned int*)(xb + (size_t)s * IN + c0);
            r[1] = 0u;
            return r;
        }
    };
    auto flushv = [&](int nn, u32x2 xs) {     // store bf16(x[nn] + acc); acc = 0
        if constexpr (XW == 2) {
            const float x0 = __builtin_bit_cast(float, xs[0] << 16);
            const float x1 = __builtin_bit_cast(float, xs[0] & 0xFFFF0000u);
            const float x2 = __builtin_bit_cast(float, xs[1] << 16);
            const float x3 = __builtin_bit_cast(float, xs[1] & 0xFFFF0000u);
            u32x2 o;
            o[0] = (unsigned)f2bf(x0 + acc[0]) | ((unsigned)f2bf(x1 + acc[1]) << 16);
            o[1] = (unsigned)f2bf(x2 + acc[2]) | ((unsigned)f2bf(x3 + acc[3]) << 16);
            *(u32x2*)(out + (size_t)nn * IN + c0) = o;
        } else {
            const float x0 = __builtin_bit_cast(float, xs[0] << 16);
            const float x1 = __builtin_bit_cast(float, xs[0] & 0xFFFF0000u);
            const unsigned int o =
                (unsigned)f2bf(x0 + acc[0]) | ((unsigned)f2bf(x1 + acc[1]) << 16);
            *(unsigned int*)(out + (size_t)nn * IN + c0) = o;
        }
#pragma unroll
        for (int j = 0; j < CPL; ++j) acc[j] = 0.0f;
    };

    // zero-degree nodes at the head of the range (immediate x loads — rare)
    int p1 = __builtin_amdgcn_readfirstlane(off[n + 1]);
    while (p1 == p) {
        flushv(n, ldx(n)); ++n;
        if (n >= nend) return;
        p1 = __builtin_amdgcn_readfirstlane(off[n + 1]);
    }
    // here: current node n non-empty, p = off[n] < p1 <= pend
    u32x2 xself = ldx(n);                     // prefetched; consumed at flush

    auto ldeL = [&](int q) -> u32x4 {        // pad reads OK: in-allocation, unused
        return ((const u32x4*)(eas + (size_t)(q + zd) * 16))[0];
    };
    auto ldeH = [&](int q) -> u32x4 {
        return ((const u32x4*)(eas + (size_t)(q + zd) * 16))[1];
    };
    auto ldsrc = [&](int q) -> int {         // CLAMPED: result is dereferenced
        const int qc = (q < N_EDGES) ? q : (N_EDGES - 1);
        return ssrc[qc + zd];
    };
    auto edge_compute = [&](u32x4 eL, u32x4 eH, u32x2 xw) {
        float m[CPL];
#pragma unroll
        for (int j = 0; j < CPL; ++j) m[j] = bias[j];
#pragma unroll
        for (int k = 0; k < 4; ++k) {
            const h2 ep = __builtin_bit_cast(h2, eL[k]);
#pragma unroll
            for (int j = 0; j < CPL; ++j)
                m[j] = DOT2(ep, __builtin_bit_cast(h2, wlo[j][k]), m[j]);
        }
#pragma unroll
        for (int k = 0; k < 4; ++k) {
            const h2 ep = __builtin_bit_cast(h2, eH[k]);
#pragma unroll
            for (int j = 0; j < CPL; ++j)
                m[j] = DOT2(ep, __builtin_bit_cast(h2, whi[j][k]), m[j]);
        }
#pragma unroll
        for (int j = 0; j < CPL; ++j) {
            const unsigned int word = xw[j >> 1];
            const float xf = __builtin_bit_cast(float,
                (j & 1) ? (word & 0xFFFF0000u) : (word << 16));
            acc[j] += fmaxf(m[j] + xf, 0.0f);
        }
    };
    // flush current node (prefetched xself) + zero-degree ties; prefetch next
    auto adv = [&]() {
        flushv(n, xself); ++n;
        while (n < nend) {
            p1 = __builtin_amdgcn_readfirstlane(off[n + 1]);
            if (p1 != p) { xself = ldx(n); break; }
            flushv(n, ldx(n)); ++n;           // zero-degree tie: immediate (rare)
        }
    };

    // depth-4 pipeline, in-place buffers, runs across node boundaries
    int sA = ldsrc(p),     sB = ldsrc(p + 1), sC = ldsrc(p + 2), sD = ldsrc(p + 3);
    u32x4 eLA = ldeL(p),     eHA = ldeH(p);
    u32x4 eLB = ldeL(p + 1), eHB = ldeH(p + 1);
    u32x4 eLC = ldeL(p + 2), eHC = ldeH(p + 2);
    u32x4 eLD = ldeL(p + 3), eHD = ldeH(p + 3);
    u32x2 xA = ldx(sA), xB = ldx(sB), xC = ldx(sC), xD = ldx(sD);
    sA = ldsrc(p + 4); sB = ldsrc(p + 5); sC = ldsrc(p + 6); sD = ldsrc(p + 7);

    for (;;) {
        edge_compute(eLA, eHA, xA);
        eLA = ldeL(p + 4); eHA = ldeH(p + 4); xA = ldx(sA); sA = ldsrc(p + 8);
        ++p; if (p == p1) adv();
        if (p >= pend) break;

        edge_compute(eLB, eHB, xB);
        eLB = ldeL(p + 4); eHB = ldeH(p + 4); xB = ldx(sB); sB = ldsrc(p + 8);
        ++p; if (p == p1) adv();
        if (p >= pend) break;

        edge_compute(eLC, eHC, xC);
        eLC = ldeL(p + 4); eHC = ldeH(p + 4); xC = ldx(sC); sC = ldsrc(p + 8);
        ++p; if (p == p1) adv();
        if (p >= pend) break;

        edge_compute(eLD, eHD, xD);
        eLD = ldeL(p + 4); eHD = ldeH(p + 4); xD = ldx(sD); sD = ldsrc(p + 8);
        ++p; if (p == p1) adv();
        if (p >= pend) break;
    }
    // safety: trailing zero-degree nodes (normally handled by adv)
    while (n < nend) { flushv(n, ldx(n)); ++n; }
}

// ---------------------------------------------------------------------------
// GEMM v3 (gemm_ldsA) — gemm_breg2 post-mortem by arithmetic: each of the 4
// waves/block (and both blockIdx.y blocks) loaded the SAME 64-row A-tile from
// global -> 8x redundant A traffic (~80 MB/gemm) in a ~150-VGPR latency-bound
// kernel (~40 us for 2.6 GFLOP + 20 MB ideal). v3: stage A [64][K] in LDS
// once per block (cooperative reg-staged 16B writes, XOR slot-swizzle
// slot^=(row&7) to break the 32-way ds_read_b128 conflict of row-major
// K-stride tiles, G4/T2), single barrier, identical MFMA fragment math and
// epilogue reading A from LDS. B stays register-resident.
// EPI 0: BN(eval)+relu -> bf16 (all rows)   EPI 1: bias+relu (rows < N)
// ---------------------------------------------------------------------------
template<int K, int EPI>
__global__ __launch_bounds__(256) void gemm_ldsA(
    const unsigned short* __restrict__ A,    // [M_PAD, K]
    const unsigned short* __restrict__ W,    // [256, K]
    const float* __restrict__ bias,
    const float* __restrict__ gsc, const float* __restrict__ bsh,
    unsigned short* __restrict__ out)        // [M_PAD, 256]
{
    constexpr int KC = K / 32;               // 4 or 8 k-chunks
    constexpr int SLOTS = K / 8;             // 16B slots per row: 16 or 32
    __shared__ unsigned short Al[64 * K];    // 16KB (K=128) / 32KB (K=256)

    const int w = threadIdx.x >> 6, lane = threadIdx.x & 63;
    const int lm = lane & 15, lq = lane >> 4;
    const int n0 = (blockIdx.y * 4 + w) * 32;
    const int m0 = blockIdx.x * 64;

    // cooperative A-tile stage: [64][K] bf16, XOR-swizzled 16B slots
#pragma unroll
    for (int i = 0; i < 64 * SLOTS / 256; ++i) {
        const int t = i * 256 + threadIdx.x;
        const int row = t / SLOTS, slot = t % SLOTS;
        const uint4 v = *(const uint4*)(A + (size_t)(m0 + row) * K + slot * 8);
        *(uint4*)((char*)Al + row * (K * 2) + ((slot ^ (row & 7)) * 16)) = v;
    }

    // B resident in registers
    bf16x8 B0[KC], B1[KC];
    {
        const unsigned short* Wp0 = W + (size_t)(n0 + lm) * K + lq * 8;
        const unsigned short* Wp1 = W + (size_t)(n0 + 16 + lm) * K + lq * 8;
#pragma unroll
        for (int c = 0; c < KC; ++c) {
            B0[c] = *(const bf16x8*)(Wp0 + c * 32);
            B1[c] = *(const bf16x8*)(Wp1 + c * 32);
        }
    }

    const float inv = rsqrtf(1.0f + 1e-5f);
    const float bc0 = bias[n0 + lm],      bc1 = bias[n0 + 16 + lm];
    const float gc0 = (EPI == 0) ? gsc[n0 + lm]      : 0.0f;
    const float gc1 = (EPI == 0) ? gsc[n0 + 16 + lm] : 0.0f;
    const float sc0 = (EPI == 0) ? bsh[n0 + lm]      : 0.0f;
    const float sc1 = (EPI == 0) ? bsh[n0 + 16 + lm] : 0.0f;

    __syncthreads();

#pragma unroll
    for (int ch = 0; ch < 4; ++ch) {
        const int row = ch * 16 + lm;
        const char* rbase = (const char*)Al + row * (K * 2);
        bf16x8 aC[KC];
#pragma unroll
        for (int c = 0; c < KC; ++c) {
            const int slot = (lq + c * 4) ^ (row & 7);
            aC[c] = *(const bf16x8*)(rbase + slot * 16);
        }

        f32x4 acc0 = (f32x4){0.f, 0.f, 0.f, 0.f};
        f32x4 acc1 = (f32x4){0.f, 0.f, 0.f, 0.f};
#pragma unroll
        for (int c = 0; c < KC; ++c) {
            acc0 = __builtin_amdgcn_mfma_f32_16x16x32_bf16(aC[c], B0[c], acc0, 0, 0, 0);
            acc1 = __builtin_amdgcn_mfma_f32_16x16x32_bf16(aC[c], B1[c], acc1, 0, 0, 0);
        }

        const int mr = m0 + ch * 16;
#pragma unroll
        for (int r = 0; r < 4; ++r) {
            const int rowo = mr + lq * 4 + r;
            if (EPI == 1 && rowo >= N_NODES) continue;
            float v0 = acc0[r] + bc0;
            float v1 = acc1[r] + bc1;
            if (EPI == 0) {
                v0 = fmaxf(v0 * inv * gc0 + sc0, 0.0f);
                v1 = fmaxf(v1 * inv * gc1 + sc1, 0.0f);
            } else {
                v0 = fmaxf(v0, 0.0f);
                v1 = fmaxf(v1, 0.0f);
            }
            out[(size_t)rowo * H + n0 + lm]      = f2bf(v0);
            out[(size_t)rowo * H + n0 + 16 + lm] = f2bf(v1);
        }
    }
}

// ---------------------------------------------------------------------------
// Parallel mean-pool: grid (192, RSPLIT). Block (g, layer, chunk) reduces
// ~rows/RSPLIT rows and atomicAdds one partial per column into pool.
// ---------------------------------------------------------------------------
#define RSPLIT 6
__global__ __launch_bounds__(256) void pool2(
    const unsigned short* __restrict__ h1, const unsigned short* __restrict__ h2,
    const unsigned short* __restrict__ h3, const int* __restrict__ start,
    float* __restrict__ pool)
{
    const int g = blockIdx.x & 63, layer = blockIdx.x >> 6;
    const unsigned short* h = (layer == 0) ? h1 : (layer == 1) ? h2 : h3;
    const int r0 = start[g], r1 = start[g + 1];
    const int nr = r1 - r0;
    if (nr <= 0) return;
    const int chunk = (nr + RSPLIT - 1) / RSPLIT;
    const int rs = r0 + blockIdx.y * chunk;
    const int re = (rs + chunk < r1) ? rs + chunk : r1;
    if (rs >= re) return;

    const int c = threadIdx.x;
    float s0 = 0.f, s1 = 0.f, s2 = 0.f, s3 = 0.f;
    int r = rs;
    for (; r + 4 <= re; r += 4) {
        s0 += bf2f(h[(size_t)(r + 0) * H + c]);
        s1 += bf2f(h[(size_t)(r + 1) * H + c]);
        s2 += bf2f(h[(size_t)(r + 2) * H + c]);
        s3 += bf2f(h[(size_t)(r + 3) * H + c]);
    }
    for (; r < re; ++r) s0 += bf2f(h[(size_t)r * H + c]);
    atomicAdd(&pool[(size_t)g * POOL_W + layer * 256 + c], s0 + s1 + s2 + s3);
}

// ---------------------------------------------------------------------------
// FC head v2 (measured win in R4; unchanged): (64 x 12) blocks, lane-parallel
// 768-dot per output + shfl_xor reduce; FC2 folded via per-wave atomicAdd.
// ---------------------------------------------------------------------------
__global__ __launch_bounds__(256) void fc_head(
    const float* __restrict__ pool, const int* __restrict__ start,
    const float* __restrict__ L1w, const float* __restrict__ L1b,
    const float* __restrict__ L2w, float* __restrict__ gsum)
{
    const int g = blockIdx.x;
    __shared__ float p[POOL_W];

    const float rc = 1.0f / fmaxf((float)(start[g + 1] - start[g]), 1.0f);
    for (int i = threadIdx.x; i < POOL_W; i += 256)
        p[i] = pool[(size_t)g * POOL_W + i] * rc;
    __syncthreads();

    const int wv = threadIdx.x >> 6, lane = threadIdx.x & 63;
    const float4* p4 = (const float4*)p;
    const float4 pa = p4[lane], pb = p4[lane + 64], pc = p4[lane + 128];

    const int ob = blockIdx.y * 64 + wv * 16;
    float part = 0.0f;
#pragma unroll 4
    for (int t = 0; t < 16; ++t) {
        const int o = ob + t;
        const float4* wr = (const float4*)(L1w + (size_t)o * POOL_W);
        const float4 a = wr[lane], b = wr[lane + 64], c = wr[lane + 128];
        float acc = a.x * pa.x + a.y * pa.y + a.z * pa.z + a.w * pa.w
                  + b.x * pb.x + b.y * pb.y + b.z * pb.z + b.w * pb.w
                  + c.x * pc.x + c.y * pc.y + c.z * pc.z + c.w * pc.w;
#pragma unroll
        for (int off = 32; off > 0; off >>= 1) acc += __shfl_xor(acc, off);
        if (lane == 0) part += fmaxf(acc + L1b[o], 0.0f) * L2w[o];
    }
    if (lane == 0) atomicAdd(&gsum[g], part);
}

__global__ __launch_bounds__(64) void sig_kernel(
    const float* __restrict__ gsum, const float* __restrict__ L2b,
    float* __restrict__ out)
{
    const int g = threadIdx.x;
    if (g < N_GRAPHS) out[g] = 1.0f / (1.0f + expf(-(gsum[g] + L2b[0])));
}

// ---------------------------------------------------------------------------
extern "C" void kernel_launch(void* const* d_in, const int* in_sizes, int n_in,
                              void* d_out, int out_size, void* d_ws, size_t ws_size,
                              hipStream_t stream)
{
    const float* x     = (const float*)d_in[0];
    const float* ea    = (const float*)d_in[1];
    const int*   src   = (const int*)d_in[2];
    const int*   dst   = (const int*)d_in[3];
    const int*   batch = (const int*)d_in[4];

    const float* We[3]; const float* be[3]; const float* Wa[3]; const float* ba[3];
    const float* gg[3]; const float* bt[3]; const float* Wb[3]; const float* bb[3];
    for (int l = 0; l < 3; ++l) {
        const int o = 5 + 8 * l;
        We[l] = (const float*)d_in[o + 0]; be[l] = (const float*)d_in[o + 1];
        Wa[l] = (const float*)d_in[o + 2]; ba[l] = (const float*)d_in[o + 3];
        gg[l] = (const float*)d_in[o + 4]; bt[l] = (const float*)d_in[o + 5];
        Wb[l] = (const float*)d_in[o + 6]; bb[l] = (const float*)d_in[o + 7];
    }
    const float* L1w = (const float*)d_in[29];
    const float* L1b = (const float*)d_in[30];
    const float* L2w = (const float*)d_in[31];
    const float* L2b = (const float*)d_in[32];

    // ---- workspace layout ----
    float* pool   = (float*)d_ws;                              // 64*768
    float* gsum   = pool + (size_t)N_GRAPHS * POOL_W;          // 64 (zeroed with pool)
    int*   deg    = (int*)(gsum + N_GRAPHS);                   // N
    int*   off    = deg + N_NODES;                             // N+1
    int*   cursor = off + N_NODES + 1;                         // N
    int*   start  = cursor + N_NODES;                          // 72
    int*   cmap   = start + 72;                                // NCHUNK+1
    int*   ssrc   = (int*)((((uintptr_t)(cmap + NCHUNK + 1)) + 31) & ~(uintptr_t)31);  // E+16 ints, CSR
    unsigned short* eas = (unsigned short*)((((uintptr_t)(ssrc + N_EDGES + 16)) + 31) & ~(uintptr_t)31); // [E+16,16] f16 CSR
    unsigned short* xb = (unsigned short*)((((uintptr_t)(eas + (size_t)(N_EDGES + 16) * 16)) + 31) & ~(uintptr_t)31);
    unsigned short* u  = xb + (size_t)M_PAD * DIN;             // [M_PAD,256] (layer1 uses 128)
    unsigned short* tT = u  + (size_t)M_PAD * H;               // [M_PAD,256] intermediate
    unsigned short* h1 = tT + (size_t)M_PAD * H;
    unsigned short* h2 = h1 + (size_t)M_PAD * H;
    unsigned short* h3 = h2 + (size_t)M_PAD * H;
    unsigned short* wbf[6];
    wbf[0] = h3 + (size_t)M_PAD * H;                           // Wa1 [256,128]
    wbf[1] = wbf[0] + H * DIN;
    for (int i = 2; i < 6; ++i) wbf[i] = wbf[i - 1] + H * H;
    unsigned short* weh[3];
    weh[0] = wbf[5] + H * H;                                   // We1 [128,16] f16
    weh[1] = weh[0] + DIN * 16;                                // We2 [256,16] f16
    weh[2] = weh[1] + H * 16;                                  // We3 [256,16] f16

    // batched converts + deg/pool+gsum zeroing in one launch (12 jobs)
    CvtJobs jobs;
    jobs.j[0]  = { x,       xb,                    N_NODES * DIN / 4,       0 };
    jobs.j[1]  = { Wa[0],   wbf[0],                H * DIN / 4,             0 };
    jobs.j[2]  = { Wb[0],   wbf[1],                H * H / 4,               0 };
    jobs.j[3]  = { Wa[1],   wbf[2],                H * H / 4,               0 };
    jobs.j[4]  = { Wb[1],   wbf[3],                H * H / 4,               0 };
    jobs.j[5]  = { Wa[2],   wbf[4],                H * H / 4,               0 };
    jobs.j[6]  = { Wb[2],   wbf[5],                H * H / 4,               0 };
    jobs.j[7]  = { nullptr, (unsigned short*)deg,  N_NODES * 4 / 8,         2 };  // zero N ints
    jobs.j[8]  = { nullptr, (unsigned short*)pool, (N_GRAPHS * POOL_W + N_GRAPHS) * 4 / 8, 2 }; // zero pool+gsum
    jobs.j[9]  = { We[0],   weh[0],                DIN * 16 / 4,            1 };
    jobs.j[10] = { We[1],   weh[1],                H * 16 / 4,              1 };
    jobs.j[11] = { We[2],   weh[2],                H * 16 / 4,              1 };
    cvt_all<<<dim3(320, 12), 256, 0, stream>>>(jobs);

    // CSR + graph boundaries; chunk map; scatter builds CSR-sorted (src, ea_f16)
    hist_kernel<<<(N_EDGES + 255) / 256, 256, 0, stream>>>(dst, deg);
    scan_kernel<<<1, 1024, 0, stream>>>(deg, off, cursor, batch, start);
    chunkmap_kernel<<<(NCHUNK + 256) / 256, 256, 0, stream>>>(off, cmap);
    scatter_kernel<<<(N_EDGES + 255) / 256, 256, 0, stream>>>(src, dst, ea, cursor, ssrc, eas);

    const int  agrid = NCHUNK / 4;              // agg3: 1 chunk/wave, 4 waves/block
    const dim3 ggrid(M_PAD / 64, 2);            // (313, 2)

    // ---- layer 1 (in=128) ----
    agg3<DIN><<<agrid, 256, 0, stream>>>(xb, eas, ssrc, off, cmap, weh[0], be[0], u);
    gemm_ldsA<DIN, 0><<<ggrid, 256, 0, stream>>>(u, wbf[0], ba[0], gg[0], bt[0], tT);
    gemm_ldsA<H,   1><<<ggrid, 256, 0, stream>>>(tT, wbf[1], bb[0], nullptr, nullptr, h1);
    // ---- layer 2 ----
    agg3<H><<<agrid, 256, 0, stream>>>(h1, eas, ssrc, off, cmap, weh[1], be[1], u);
    gemm_ldsA<H, 0><<<ggrid, 256, 0, stream>>>(u, wbf[2], ba[1], gg[1], bt[1], tT);
    gemm_ldsA<H, 1><<<ggrid, 256, 0, stream>>>(tT, wbf[3], bb[1], nullptr, nullptr, h2);
    // ---- layer 3 ----
    agg3<H><<<agrid, 256, 0, stream>>>(h2, eas, ssrc, off, cmap, weh[2], be[2], u);
    gemm_ldsA<H, 0><<<ggrid, 256, 0, stream>>>(u, wbf[4], ba[2], gg[2], bt[2], tT);
    gemm_ldsA<H, 1><<<ggrid, 256, 0, stream>>>(tT, wbf[5], bb[2], nullptr, nullptr, h3);

    // parallel mean-pool + head
    pool2<<<dim3(3 * N_GRAPHS, RSPLIT), 256, 0, stream>>>(h1, h2, h3, start, pool);
    fc_head<<<dim3(N_GRAPHS, POOL_W / 64), 256, 0, stream>>>(pool, start, L1w, L1b, L2w, gsum);
    sig_kernel<<<1, 64, 0, stream>>>(gsum, L2b, (float*)d_out);
}